// Round 1
// baseline (311.473 us; speedup 1.0000x reference)
//
#include <hip/hip_runtime.h>

// DART_Net fused kernel, MI355X (gfx950).
// B=64, N=128, M=64, LH=LO=128. Output [B*N] fp32.
//
// Structure: grid 512 blocks x 256 threads, G=16 atoms (b,n pairs) per block.
// Layer2 (128x128) of each species MLP runs on bf16 MFMA 16x16x32 with the
// W2 column-half held in registers per wave (2x2 wave split over the 64x128
// per-atom output). Layer1 (3->128) + celu computed per-lane directly in
// A-fragment layout. atm accumulated in LDS, head MLP in fp32.

typedef __attribute__((ext_vector_type(8))) short short8;   // bf16x8 frag (4 VGPR)
typedef __attribute__((ext_vector_type(4))) float f32x4;    // acc frag / float4

#define G_ 16

struct DartParams {
  const float* x[4];    // aj, ak, al, ai
  const float* W1[4];   // [128][3]  (j,k,l,i)
  const float* b1[4];   // [128]
  const float* W2[4];   // [128][128]
  const float* b2[4];   // [128]
  const float* HW[4];   // 64x128, 32x64, 16x32, 1x16
  const float* Hb[4];
  float* out;
};

__device__ __forceinline__ float celu01(float z) {
  // celu(z, alpha=0.1) = max(z,0) + min(0.1*(exp(10z)-1), 0)
  float e = __builtin_amdgcn_exp2f(z * 14.42695040888963f);  // exp(10z)
  return fmaxf(z, 0.0f) + fminf(fmaf(0.1f, e, -0.1f), 0.0f);
}

__device__ __forceinline__ short f2bf(float f) {
  unsigned u = __builtin_bit_cast(unsigned, f);
  u += 0x7fffu + ((u >> 16) & 1u);   // RNE
  return (short)(u >> 16);
}

extern "C" __global__ __launch_bounds__(256, 2)
void dart_fused(DartParams p) {
  __shared__ f32x4 sW1[4][128];      // {w0,w1,w2,b} per channel
  __shared__ float sB2[4][128];
  __shared__ float sAtm[G_][128];
  __shared__ float sImask[G_];
  __shared__ float sH1[G_][64];
  __shared__ float sH2[G_][32];
  __shared__ float sH3[G_][16];

  const int t    = threadIdx.x;
  const int lane = t & 63;
  const int wave = t >> 6;       // 0..3
  const int wr   = wave >> 1;    // row half (0,1)
  const int wc   = wave & 1;     // col half (0,1)
  const int lq   = lane >> 4;    // lane quarter
  const int lr   = lane & 15;
  const int atom0 = (int)blockIdx.x * G_;

  // ---- stage layer-1 weights (packed float4) and layer-2 biases ----
#pragma unroll
  for (int s = 0; s < 4; ++s) {
    if (t < 128) {
      const float* w = p.W1[s] + t * 3;
      f32x4 v;
      v.x = w[0]; v.y = w[1]; v.z = w[2]; v.w = p.b1[s][t];
      sW1[s][t] = v;
      sB2[s][t] = p.b2[s][t];
    }
  }
  for (int i = t; i < G_ * 128; i += 256) (&sAtm[0][0])[i] = 0.0f;
  __syncthreads();

  short8 bfr[4][4];   // B fragments [ob][kb], held across the atom loop

  // ---------------- species j, k, l ----------------
#pragma unroll
  for (int s = 0; s < 3; ++s) {
    const float* W2 = p.W2[s];
#pragma unroll
    for (int ob = 0; ob < 4; ++ob) {
#pragma unroll
      for (int kb = 0; kb < 4; ++kb) {
        const f32x4* src = (const f32x4*)(W2 + (wc * 64 + ob * 16 + lr) * 128 + kb * 32 + lq * 8);
        f32x4 lo = src[0], hi = src[1];
        short8 f;
        f[0] = f2bf(lo.x); f[1] = f2bf(lo.y); f[2] = f2bf(lo.z); f[3] = f2bf(lo.w);
        f[4] = f2bf(hi.x); f[5] = f2bf(hi.y); f[6] = f2bf(hi.z); f[7] = f2bf(hi.w);
        bfr[ob][kb] = f;
      }
    }
    float b2r[4];
#pragma unroll
    for (int ob = 0; ob < 4; ++ob) b2r[ob] = sB2[s][wc * 64 + ob * 16 + lr];

    const float* X = p.x[s];
#pragma unroll 1
    for (int g = 0; g < G_; ++g) {
      const int rowbase = (atom0 + g) * 64;
      // ---- load x rows owned by this lane's A fragments ----
      float x0[2], x1[2], x2[2], maskA[2];
#pragma unroll
      for (int rb = 0; rb < 2; ++rb) {
        const float* xp = X + (rowbase + wr * 32 + rb * 16 + lr) * 3;
        x0[rb] = xp[0]; x1[rb] = xp[1]; x2[rb] = xp[2];
        maskA[rb] = ((x0[rb] + x1[rb] + x2[rb]) != 0.0f) ? 1.0f : 0.0f;
      }
      // masks for the C-fragment rows (row = rb*16 + lq*4 + j), via shuffle
      float mrow[2][4];
#pragma unroll
      for (int rb = 0; rb < 2; ++rb)
#pragma unroll
        for (int j = 0; j < 4; ++j)
          mrow[rb][j] = __shfl(maskA[rb], lq * 4 + j, 64);

      // ---- layer 1 + celu + pack, directly in A-fragment layout ----
      short8 af[2][4];
#pragma unroll
      for (int kb = 0; kb < 4; ++kb) {
        short8 f0, f1;
#pragma unroll
        for (int e = 0; e < 8; ++e) {
          f32x4 w = sW1[s][kb * 32 + lq * 8 + e];
          f0[e] = f2bf(celu01(fmaf(x0[0], w.x, fmaf(x1[0], w.y, fmaf(x2[0], w.z, w.w)))));
          f1[e] = f2bf(celu01(fmaf(x0[1], w.x, fmaf(x1[1], w.y, fmaf(x2[1], w.z, w.w)))));
        }
        af[0][kb] = f0; af[1][kb] = f1;
      }

      // ---- layer 2 GEMM (64x128 per atom, this wave: 32 rows x 64 cols) ----
      f32x4 acc[2][4];
#pragma unroll
      for (int rb = 0; rb < 2; ++rb)
#pragma unroll
        for (int ob = 0; ob < 4; ++ob) {
          f32x4 a = {0.0f, 0.0f, 0.0f, 0.0f};
#pragma unroll
          for (int kb = 0; kb < 4; ++kb)
            a = __builtin_amdgcn_mfma_f32_16x16x32_bf16(af[rb][kb], bfr[ob][kb], a, 0, 0, 0);
          acc[rb][ob] = a;
        }

      // ---- bias + celu + mask + row-sum -> atm ----
#pragma unroll
      for (int ob = 0; ob < 4; ++ob) {
        const int col = wc * 64 + ob * 16 + lr;
        float part = 0.0f;
#pragma unroll
        for (int rb = 0; rb < 2; ++rb)
#pragma unroll
          for (int j = 0; j < 4; ++j)
            part += celu01(acc[rb][ob][j] + b2r[ob]) * mrow[rb][j];
        part += __shfl_xor(part, 16, 64);
        part += __shfl_xor(part, 32, 64);
        if (lane < 16) atomicAdd(&sAtm[g][col], part);
      }
    }
  }

  // ---------------- species i: one 16-row GEMM (rows = atoms) ----------------
  {
    const float* W2 = p.W2[3];
#pragma unroll
    for (int ob = 0; ob < 4; ++ob) {
#pragma unroll
      for (int kb = 0; kb < 4; ++kb) {
        const f32x4* src = (const f32x4*)(W2 + (wc * 64 + ob * 16 + lr) * 128 + kb * 32 + lq * 8);
        f32x4 lo = src[0], hi = src[1];
        short8 f;
        f[0] = f2bf(lo.x); f[1] = f2bf(lo.y); f[2] = f2bf(lo.z); f[3] = f2bf(lo.w);
        f[4] = f2bf(hi.x); f[5] = f2bf(hi.y); f[6] = f2bf(hi.z); f[7] = f2bf(hi.w);
        bfr[ob][kb] = f;
      }
    }
    const float* xp = p.x[3] + (atom0 + lr) * 3;
    const float x0 = xp[0], x1 = xp[1], x2 = xp[2];
    const float maskI = ((x0 + x1 + x2) != 0.0f) ? 1.0f : 0.0f;

    short8 af[4];
#pragma unroll
    for (int kb = 0; kb < 4; ++kb) {
      short8 f;
#pragma unroll
      for (int e = 0; e < 8; ++e) {
        f32x4 w = sW1[3][kb * 32 + lq * 8 + e];
        f[e] = f2bf(celu01(fmaf(x0, w.x, fmaf(x1, w.y, fmaf(x2, w.z, w.w)))));
      }
      af[kb] = f;
    }
    f32x4 acc[4];
#pragma unroll
    for (int ob = 0; ob < 4; ++ob) {
      f32x4 a = {0.0f, 0.0f, 0.0f, 0.0f};
#pragma unroll
      for (int kb = 0; kb < 4; ++kb)
        a = __builtin_amdgcn_mfma_f32_16x16x32_bf16(af[kb], bfr[ob][kb], a, 0, 0, 0);
      acc[ob] = a;
    }
    __syncthreads();   // all j/k/l atomics complete before exclusive adds
    if (wr == 0) {
      if (wave == 0 && lane < 16) sImask[lr] = maskI;
#pragma unroll
      for (int ob = 0; ob < 4; ++ob) {
        const int col = wc * 64 + ob * 16 + lr;
        const float b2v = sB2[3][col];
#pragma unroll
        for (int j = 0; j < 4; ++j) {
          const int g = lq * 4 + j;
          float m = __shfl(maskI, g, 64);
          sAtm[g][col] += celu01(acc[ob][j] + b2v) * m;
        }
      }
    }
    __syncthreads();
  }

  // ---------------- head MLP: 128 -> 64 -> 32 -> 16 -> 1 ----------------
  {
    const int g = t >> 4, u = t & 15;
    const f32x4* atm4 = (const f32x4*)sAtm[g];
#pragma unroll
    for (int rep = 0; rep < 4; ++rep) {
      const int o = rep * 16 + u;
      const f32x4* w4 = (const f32x4*)(p.HW[0] + o * 128);
      float z = p.Hb[0][o];
#pragma unroll 8
      for (int c = 0; c < 32; ++c) {
        f32x4 a = atm4[c], w = w4[c];
        z = fmaf(a.x, w.x, fmaf(a.y, w.y, fmaf(a.z, w.z, fmaf(a.w, w.w, z))));
      }
      sH1[g][o] = celu01(z);
    }
    __syncthreads();
    const f32x4* h14 = (const f32x4*)sH1[g];
#pragma unroll
    for (int rep = 0; rep < 2; ++rep) {
      const int o = rep * 16 + u;
      const f32x4* w4 = (const f32x4*)(p.HW[1] + o * 64);
      float z = p.Hb[1][o];
#pragma unroll
      for (int c = 0; c < 16; ++c) {
        f32x4 a = h14[c], w = w4[c];
        z = fmaf(a.x, w.x, fmaf(a.y, w.y, fmaf(a.z, w.z, fmaf(a.w, w.w, z))));
      }
      sH2[g][o] = celu01(z);
    }
    __syncthreads();
    {
      const f32x4* h24 = (const f32x4*)sH2[g];
      const f32x4* w4 = (const f32x4*)(p.HW[2] + u * 32);
      float z = p.Hb[2][u];
#pragma unroll
      for (int c = 0; c < 8; ++c) {
        f32x4 a = h24[c], w = w4[c];
        z = fmaf(a.x, w.x, fmaf(a.y, w.y, fmaf(a.z, w.z, fmaf(a.w, w.w, z))));
      }
      sH3[g][u] = celu01(z);
    }
    __syncthreads();
    if (u == 0) {
      const f32x4* h34 = (const f32x4*)sH3[g];
      const f32x4* w4 = (const f32x4*)p.HW[3];
      float z = p.Hb[3][0];
#pragma unroll
      for (int c = 0; c < 4; ++c) {
        f32x4 a = h34[c], w = w4[c];
        z = fmaf(a.x, w.x, fmaf(a.y, w.y, fmaf(a.z, w.z, fmaf(a.w, w.w, z))));
      }
      p.out[atom0 + g] = z * sImask[g];
    }
  }
}

extern "C" void kernel_launch(void* const* d_in, const int* in_sizes, int n_in,
                              void* d_out, int out_size, void* d_ws, size_t ws_size,
                              hipStream_t stream) {
  (void)in_sizes; (void)n_in; (void)out_size; (void)d_ws; (void)ws_size;
  DartParams p;
  // dict order: ai aj ak al | Wi1 bi1 Wi2 bi2 | Wj1 bj1 Wj2 bj2 | Wk1 bk1 Wk2 bk2
  //             | Wl1 bl1 Wl2 bl2 | W1 b1 W2 b2 W3 b3 W4 b4
  p.x[0] = (const float*)d_in[1];   // aj
  p.x[1] = (const float*)d_in[2];   // ak
  p.x[2] = (const float*)d_in[3];   // al
  p.x[3] = (const float*)d_in[0];   // ai
  p.W1[0] = (const float*)d_in[8];  p.b1[0] = (const float*)d_in[9];
  p.W2[0] = (const float*)d_in[10]; p.b2[0] = (const float*)d_in[11];
  p.W1[1] = (const float*)d_in[12]; p.b1[1] = (const float*)d_in[13];
  p.W2[1] = (const float*)d_in[14]; p.b2[1] = (const float*)d_in[15];
  p.W1[2] = (const float*)d_in[16]; p.b1[2] = (const float*)d_in[17];
  p.W2[2] = (const float*)d_in[18]; p.b2[2] = (const float*)d_in[19];
  p.W1[3] = (const float*)d_in[4];  p.b1[3] = (const float*)d_in[5];
  p.W2[3] = (const float*)d_in[6];  p.b2[3] = (const float*)d_in[7];
  p.HW[0] = (const float*)d_in[20]; p.Hb[0] = (const float*)d_in[21];
  p.HW[1] = (const float*)d_in[22]; p.Hb[1] = (const float*)d_in[23];
  p.HW[2] = (const float*)d_in[24]; p.Hb[2] = (const float*)d_in[25];
  p.HW[3] = (const float*)d_in[26]; p.Hb[3] = (const float*)d_in[27];
  p.out = (float*)d_out;

  dart_fused<<<dim3(512), dim3(256), 0, stream>>>(p);
}